// Round 18
// baseline (1134.407 us; speedup 1.0000x reference)
//
#include <hip/hip_runtime.h>
#include <cstdint>
#include <cstddef>

#define NN   256      // nodes
#define HIDD 128      // hidden
#define NB   32       // graphs per batch
#define TT   16       // timesteps
#define BSZ  (NB*NN)  // 8192 rows

struct GP {
  const float* W[8];  // s=0..3: Wi,Wf,Wc,Wo ; s=4..7: Ui,Uf,Uc,Uo
  const float* A[8];  // matching a-vectors (256,)
};

typedef __attribute__((ext_vector_type(8))) short bf16x8;
typedef __attribute__((ext_vector_type(4))) float f32x4;
typedef _Float16 f16x8 __attribute__((ext_vector_type(8)));

__device__ __forceinline__ uint16_t bf16rn(float f) {
  uint32_t u = __float_as_uint(f);
  uint32_t r = u + 0x7fffu + ((u >> 16) & 1u);
  return (uint16_t)(r >> 16);
}
__device__ __forceinline__ float bf16f(uint16_t h) {
  return __uint_as_float((uint32_t)h << 16);
}
__device__ __forceinline__ uint16_t f16b(float f) {
  union { _Float16 h; uint16_t u; } cv;
  cv.h = (_Float16)f;
  return cv.u;
}
__device__ __forceinline__ float f16f(uint16_t u) {
  union { uint16_t u; _Float16 h; } cv;
  cv.u = u;
  return (float)cv.h;
}
__device__ __forceinline__ float h4(uint2 v, int j) {
  uint32_t u = ((j < 2) ? v.x : v.y) >> ((j & 1)*16);
  return f16f((uint16_t)u);
}
__device__ __forceinline__ float fsig(float x) {
  return 1.f/(1.f + __expf(-x));
}
__device__ __forceinline__ float ftanh(float x) {
  float xc = fmaxf(-44.f, fminf(44.f, x));
  float e = __expf(-2.f*xc);
  return (1.f - e)/(1.f + e);
}

// ---------------- K0: pre-convert W[s] to fragment-ordered bf16 hi/lo ----------------
__global__ __launch_bounds__(256) void k0_convw(GP gp, uint4* __restrict__ WfH,
    uint4* __restrict__ WfL)
{
  const int s = blockIdx.x;
  const float* __restrict__ W = gp.W[s];
  const int tid = threadIdx.x;
  #pragma unroll
  for (int it = 0; it < 8; ++it) {
    int f = it*256 + tid;               // 0..2047
    int cf = f >> 8, ks = (f >> 6) & 3, l = f & 63;
    int col = cf*16 + (l & 15);
    int kbase = (ks*4 + (l >> 4))*8;
    float v[8];
    #pragma unroll
    for (int j = 0; j < 8; ++j) v[j] = W[(kbase + j)*HIDD + col];
    uint32_t uh[4], ul[4];
    #pragma unroll
    for (int j = 0; j < 4; ++j) {
      uint16_t h0 = bf16rn(v[2*j]), h1 = bf16rn(v[2*j+1]);
      uint16_t l0 = bf16rn(v[2*j]   - bf16f(h0));
      uint16_t l1 = bf16rn(v[2*j+1] - bf16f(h1));
      uh[j] = (uint32_t)h0 | ((uint32_t)h1 << 16);
      ul[j] = (uint32_t)l0 | ((uint32_t)l1 << 16);
    }
    WfH[s*2048 + f] = make_uint4(uh[0], uh[1], uh[2], uh[3]);
    WfL[s*2048 + f] = make_uint4(ul[0], ul[1], ul[2], ul[3]);
  }
}

// ---------------- K0L: pre-convert linh^T to fragment-ordered bf16 hi/lo ----------------
__global__ __launch_bounds__(256) void k0_lh(const float* __restrict__ lhw,
    uint4* __restrict__ LhH, uint4* __restrict__ LhL)
{
  const int tid = threadIdx.x;
  #pragma unroll
  for (int it = 0; it < 8; ++it) {
    int f = it*256 + tid;               // 0..2047
    int cf = f >> 8, ks = (f >> 6) & 3, l = f & 63;
    int col = cf*16 + (l & 15);
    int kbase = (ks*4 + (l >> 4))*8;
    float v[8];
    #pragma unroll
    for (int j = 0; j < 8; ++j) v[j] = lhw[col*HIDD + kbase + j];
    uint32_t uh[4], ul[4];
    #pragma unroll
    for (int j = 0; j < 4; ++j) {
      uint16_t h0 = bf16rn(v[2*j]), h1 = bf16rn(v[2*j+1]);
      uint16_t l0 = bf16rn(v[2*j]   - bf16f(h0));
      uint16_t l1 = bf16rn(v[2*j+1] - bf16f(h1));
      uh[j] = (uint32_t)h0 | ((uint32_t)h1 << 16);
      ul[j] = (uint32_t)l0 | ((uint32_t)l1 << 16);
    }
    LhH[f] = make_uint4(uh[0], uh[1], uh[2], uh[3]);
    LhL[f] = make_uint4(ul[0], ul[1], ul[2], ul[3]);
  }
}

// ---------------- K0b: Wa[s][k] = sum_c W[k][c]*a{1,2}[c] ----------------
__global__ __launch_bounds__(128) void k0_wa(GP gp, float* __restrict__ Wa)
{
  const int s = blockIdx.x, k = threadIdx.x;
  const float* __restrict__ W = gp.W[s];
  const float* __restrict__ A = gp.A[s];
  float d1 = 0.f, d2 = 0.f;
  #pragma unroll 4
  for (int c = 0; c < HIDD; ++c) {
    float wv = W[k*HIDD + c];
    d1 += wv*A[c];
    d2 += wv*A[HIDD + c];
  }
  Wa[s*256 + k]       = d1;
  Wa[s*256 + 128 + k] = d2;
}

// ---------------- K1: src @ W_s -> H fragments (fp16) + f1/f2, NG gates/block ----------------
// 64-row tiles, 256 threads. Direct fragment stores from MFMA acc registers.
template<int NG>
__global__ __launch_bounds__(256) void k1_gemm(const float* __restrict__ x,
    const float* __restrict__ hstate, const uint4* __restrict__ WfH,
    const uint4* __restrict__ WfL, const float* __restrict__ Wa,
    uint4* __restrict__ HfO, float* __restrict__ f12,
    int sBase, int wside, int tArg)
{
  const int t = wside ? blockIdx.y : tArg;
  const int s0 = wside ? 0 : (sBase + blockIdx.y*NG);
  const int row0 = blockIdx.x * 64;
  const int b = row0 >> 8;
  const int kc = (row0 >> 6) & 3;
  const int tid = threadIdx.x, lane = tid & 63, w = tid >> 6;
  __shared__ __align__(16) uint4 AH[1024];       // 16 KB source hi
  __shared__ __align__(16) uint4 AL[1024];       // 16 KB source lo
  __shared__ float red1[2][4][64], red2[2][4][64];  // parity double-buffer, 4 KB
  const bool useX = wside || (s0 < 4);

  // stage source rows once: hi/lo bf16 (16B-block XOR swizzle by row&7)
  #pragma unroll
  for (int it = 0; it < 4; ++it) {
    int linear = it*256 + tid;          // 0..1023
    int r = linear >> 4, blk = linear & 15;
    const float4* p = useX
      ? reinterpret_cast<const float4*>(x + (size_t)(row0 + r)*(TT*HIDD) + (size_t)t*HIDD)
      : reinterpret_cast<const float4*>(hstate + (size_t)(row0 + r)*HIDD);
    float4 v0 = p[blk*2], v1 = p[blk*2 + 1];
    float vv[8] = {v0.x, v0.y, v0.z, v0.w, v1.x, v1.y, v1.z, v1.w};
    uint32_t uh[4], ul[4];
    #pragma unroll
    for (int j = 0; j < 4; ++j) {
      uint16_t h0 = bf16rn(vv[2*j]), h1 = bf16rn(vv[2*j+1]);
      uint16_t l0 = bf16rn(vv[2*j]   - bf16f(h0));
      uint16_t l1 = bf16rn(vv[2*j+1] - bf16f(h1));
      uh[j] = (uint32_t)h0 | ((uint32_t)h1 << 16);
      ul[j] = (uint32_t)l0 | ((uint32_t)l1 << 16);
    }
    int dst = r*16 + (blk ^ (r & 7));
    AH[dst] = make_uint4(uh[0], uh[1], uh[2], uh[3]);
    AL[dst] = make_uint4(ul[0], ul[1], ul[2], ul[3]);
  }
  __syncthreads();

  // A-fragment register loads once (shared across gates)
  const int kg = lane >> 4;
  bf16x8 ah[4], al[4];
  {
    int i = w*16 + (lane & 15);
    #pragma unroll
    for (int ks = 0; ks < 4; ++ks) {
      int blk = (ks*4 + kg) ^ (i & 7);
      ah[ks] = *reinterpret_cast<const bf16x8*>(&AH[i*16 + blk]);
      al[ks] = *reinterpret_cast<const bf16x8*>(&AL[i*16 + blk]);
    }
  }
  const int frow = tid & 63, kq = tid >> 6;
  // direct-store geometry (constant per thread)
  const int jlb = w*16 + (lane >> 4)*4;                 // local row base
  const int ksS = jlb >> 5;                             // fragment k-step
  const int l2S = (((jlb & 31) >> 3) << 4) | (lane & 15);
  const int hoff = (jlb & 4)*2;                         // byte offset of uint2 half

  #pragma unroll 1
  for (int gi = 0; gi < NG; ++gi) {
    const int s = wside ? gi : (s0 + gi);
    const int tIdx = wside ? (t*4 + gi) : (s - sBase);
    const int par = gi & 1;
    // f1/f2 partials (LDS reads; AH/AL stay intact)
    {
      const float* __restrict__ wa = Wa + s*256;
      float d1 = 0.f, d2 = 0.f;
      #pragma unroll
      for (int bb = 0; bb < 4; ++bb) {
        int bi = kq*4 + bb;
        uint4 vh = AH[frow*16 + (bi ^ (frow & 7))];
        uint4 vl = AL[frow*16 + (bi ^ (frow & 7))];
        #pragma unroll
        for (int j = 0; j < 4; ++j) {
          uint32_t uh = (&vh.x)[j], ul2 = (&vl.x)[j];
          float e0 = __uint_as_float(uh << 16) + __uint_as_float(ul2 << 16);
          float e1 = __uint_as_float(uh & 0xffff0000u) + __uint_as_float(ul2 & 0xffff0000u);
          int k0 = bi*8 + j*2;
          d1 += e0*wa[k0]     + e1*wa[k0+1];
          d2 += e0*wa[128+k0] + e1*wa[128+k0+1];
        }
      }
      red1[par][kq][frow] = d1; red2[par][kq][frow] = d2;
    }
    // MFMA (split bf16: hh + lh + hl)
    f32x4 acc[8];
    #pragma unroll
    for (int c = 0; c < 8; ++c) acc[c] = (f32x4){0.f, 0.f, 0.f, 0.f};
    const uint4* __restrict__ BH = WfH + s*2048;
    const uint4* __restrict__ BL = WfL + s*2048;
    #pragma unroll
    for (int cf = 0; cf < 8; ++cf) {
      bf16x8 bh[4], bl[4];
      #pragma unroll
      for (int ks = 0; ks < 4; ++ks) {
        bh[ks] = *reinterpret_cast<const bf16x8*>(&BH[(cf*4 + ks)*64 + lane]);
        bl[ks] = *reinterpret_cast<const bf16x8*>(&BL[(cf*4 + ks)*64 + lane]);
      }
      #pragma unroll
      for (int ks = 0; ks < 4; ++ks) {
        acc[cf] = __builtin_amdgcn_mfma_f32_16x16x32_bf16(ah[ks], bh[ks], acc[cf], 0, 0, 0);
        acc[cf] = __builtin_amdgcn_mfma_f32_16x16x32_bf16(al[ks], bh[ks], acc[cf], 0, 0, 0);
        acc[cf] = __builtin_amdgcn_mfma_f32_16x16x32_bf16(ah[ks], bl[ks], acc[cf], 0, 0, 0);
      }
    }
    __syncthreads();   // red[par] visible to f12-store threads
    if (tid < 64) {
      float* fb = f12 + (size_t)tIdx*2*BSZ;
      fb[row0 + tid]       = red1[par][0][tid] + red1[par][1][tid] + red1[par][2][tid] + red1[par][3][tid];
      fb[BSZ + row0 + tid] = red2[par][0][tid] + red2[par][1][tid] + red2[par][2][tid] + red2[par][3][tid];
    }
    // direct fragment stores (coalesced uint2 per cf)
    {
      char* HfB = reinterpret_cast<char*>(HfO + (size_t)(tIdx*NB + b)*4096);
      #pragma unroll
      for (int cf = 0; cf < 8; ++cf) {
        uint16_t hh[4];
        #pragma unroll
        for (int ii = 0; ii < 4; ++ii) hh[ii] = f16b(acc[cf][ii]);
        size_t fg = (size_t)((kc*2 + ksS)*8 + cf)*64 + l2S;
        *reinterpret_cast<uint2*>(HfB + fg*16 + hoff) =
            make_uint2((uint32_t)hh[0] | ((uint32_t)hh[1] << 16),
                       (uint32_t)hh[2] | ((uint32_t)hh[3] << 16));
      }
    }
  }
}

// ---------------- K2: gat[s] = elu(softmax(leaky(f1_i+f2_j)) @ h) -> fp16 ----------------
// Double-buffered P: gen(kc+1) overlaps MFMA(kc); one barrier per kc.
__global__ __launch_bounds__(256) void k2_attn(
    const uint4* __restrict__ HfW, const uint4* __restrict__ HfU,
    const float* __restrict__ f12W, const float* __restrict__ f12U,
    uint16_t* __restrict__ gatH, int t, int pre)
{
  const int s = blockIdx.y;
  const int b = blockIdx.x;
  const int roff = blockIdx.z * 64;
  const int tid = threadIdx.x, lane = tid & 63, w = tid >> 6;
  const int rl = tid & 63, qh = tid >> 6;     // row-local, j-quarter
  __shared__ __align__(16) float f2L[NN];
  __shared__ __align__(16) float sums[256];
  __shared__ __align__(16) uint16_t Pb[2][64*64];   // 16 KB double buffer
  const uint4 *BH;
  const float* fb;
  if (pre && s < 4) {
    size_t tg = (size_t)(t*4 + s);
    BH = HfW + (tg*NB + b)*4096;
    fb = f12W + tg*2*BSZ;
  } else {
    size_t tg = (size_t)(s - (pre ? 4 : 0));
    BH = HfU + (tg*NB + b)*4096;
    fb = f12U + tg*2*BSZ;
  }
  f2L[tid] = fb[BSZ + b*NN + tid];
  const float f1v = fb[b*NN + roff + rl];
  __syncthreads();

  const float4* f24 = reinterpret_cast<const float4*>(f2L);
  float ssum = 0.f;
  f32x4 acc[8];
  #pragma unroll
  for (int c = 0; c < 8; ++c) acc[c] = (f32x4){0.f, 0.f, 0.f, 0.f};
  const int kg = lane >> 4;

  // P-gen lambda-equivalent: writes 2 swizzled uint4 rows for chunk kc into buf
  #define GENP(kc_, buf_)                                                        \
    {                                                                            \
      char* PB = reinterpret_cast<char*>(Pb[buf_]);                              \
      _Pragma("unroll")                                                          \
      for (int bb = 0; bb < 2; ++bb) {                                           \
        int blk = qh*2 + bb;                                                     \
        float4 va = f24[(kc_)*16 + blk*2];                                       \
        float4 vb = f24[(kc_)*16 + blk*2 + 1];                                   \
        float e0 = f1v + va.x; e0 = e0 > 0.f ? e0 : 0.01f*e0;                    \
        float e1 = f1v + va.y; e1 = e1 > 0.f ? e1 : 0.01f*e1;                    \
        float e2 = f1v + va.z; e2 = e2 > 0.f ? e2 : 0.01f*e2;                    \
        float e3 = f1v + va.w; e3 = e3 > 0.f ? e3 : 0.01f*e3;                    \
        float e4 = f1v + vb.x; e4 = e4 > 0.f ? e4 : 0.01f*e4;                    \
        float e5 = f1v + vb.y; e5 = e5 > 0.f ? e5 : 0.01f*e5;                    \
        float e6 = f1v + vb.z; e6 = e6 > 0.f ? e6 : 0.01f*e6;                    \
        float e7 = f1v + vb.w; e7 = e7 > 0.f ? e7 : 0.01f*e7;                    \
        float p0 = __expf(e0), p1 = __expf(e1), p2 = __expf(e2), p3 = __expf(e3);\
        float p4 = __expf(e4), p5 = __expf(e5), p6 = __expf(e6), p7 = __expf(e7);\
        ssum += (p0 + p1) + (p2 + p3) + ((p4 + p5) + (p6 + p7));                 \
        uint32_t u0 = (uint32_t)f16b(p0) | ((uint32_t)f16b(p1) << 16);           \
        uint32_t u1 = (uint32_t)f16b(p2) | ((uint32_t)f16b(p3) << 16);           \
        uint32_t u2 = (uint32_t)f16b(p4) | ((uint32_t)f16b(p5) << 16);           \
        uint32_t u3 = (uint32_t)f16b(p6) | ((uint32_t)f16b(p7) << 16);           \
        *reinterpret_cast<uint4*>(PB + rl*128 + ((blk ^ (rl & 7)) << 4)) =       \
            make_uint4(u0, u1, u2, u3);                                          \
      }                                                                          \
    }

  GENP(0, 0);
  __syncthreads();
  #pragma unroll
  for (int kc = 0; kc < 4; ++kc) {
    if (kc < 3) GENP(kc + 1, (kc + 1) & 1);
    const char* PB = reinterpret_cast<const char*>(Pb[kc & 1]);
    #pragma unroll
    for (int ks = 0; ks < 2; ++ks) {
      int i = w*16 + (lane & 15);
      int blk = (ks*4 + kg) ^ (i & 7);
      f16x8 af = *reinterpret_cast<const f16x8*>(PB + i*128 + blk*16);
      #pragma unroll
      for (int c = 0; c < 8; ++c) {
        size_t fg = (size_t)((kc*2 + ks)*8 + c)*64 + lane;
        f16x8 bh = *reinterpret_cast<const f16x8*>(&BH[fg]);
        acc[c] = __builtin_amdgcn_mfma_f32_16x16x32_f16(af, bh, acc[c], 0, 0, 0);
      }
    }
    __syncthreads();
  }
  #undef GENP
  sums[tid] = ssum;
  __syncthreads();

  uint16_t* __restrict__ gout = gatH + ((size_t)s*BSZ + (size_t)b*NN)*HIDD;
  {
    int lrb = w*16 + (lane >> 4)*4;
    int row = roff + lrb;
    #pragma unroll
    for (int ii = 0; ii < 4; ++ii) {
      float rs = 1.f / (sums[lrb + ii] + sums[64 + lrb + ii] +
                        sums[128 + lrb + ii] + sums[192 + lrb + ii]);
      #pragma unroll
      for (int c = 0; c < 8; ++c) {
        int col = c*16 + (lane & 15);
        float v = acc[c][ii] * rs;
        v = v > 0.f ? v : (__expf(v) - 1.f);
        gout[(size_t)(row + ii)*HIDD + col] = f16b(v);
      }
    }
  }
}

// ---------------- K3: LSTM gate combine (fp16 gat) + pool partials ----------------
__global__ __launch_bounds__(256) void k3_gates(const uint16_t* __restrict__ gatH,
    const float4* __restrict__ bi4, const float4* __restrict__ bf4,
    const float4* __restrict__ bc4, const float4* __restrict__ bo4,
    float4* __restrict__ c4, float4* __restrict__ hm4, float4* __restrict__ outc4,
    const float* __restrict__ pw, float4* __restrict__ qpart)
{
  const size_t S4h = (size_t)BSZ*HIDD/4;     // uint2 (4 halves) per buffer
  const int tid = threadIdx.x;
  size_t idx = (size_t)blockIdx.x*256 + tid;
  int hc = (int)(idx & 31);
  const uint2* gH = reinterpret_cast<const uint2*>(gatH);
  uint2 g0 = gH[idx],          g1 = gH[S4h + idx];
  uint2 g2 = gH[2*S4h + idx],  g3 = gH[3*S4h + idx];
  uint2 g4 = gH[4*S4h + idx],  g5 = gH[5*S4h + idx];
  uint2 g6 = gH[6*S4h + idx],  g7 = gH[7*S4h + idx];
  float4 Bi = bi4[hc], Bf = bf4[hc], Bc = bc4[hc], Bo = bo4[hc];
  float4 cv = c4[idx], hv, cn;
  #pragma unroll
  for (int j = 0; j < 4; ++j) {
    float xi = h4(g0, j) + h4(g4, j) + (&Bi.x)[j];
    float xf = h4(g1, j) + h4(g5, j) + (&Bf.x)[j];
    float xc = h4(g2, j) + h4(g6, j) + (&Bc.x)[j];
    float xo = h4(g3, j) + h4(g7, j) + (&Bo.x)[j];
    float it = fsig(xi);
    float ft = fsig(xf);
    float gt = ftanh(xc);
    float ot = fsig(xo);
    float c = ft*(&cv.x)[j] + it*gt;
    (&cn.x)[j] = c;
    (&hv.x)[j] = ot*ftanh(c);
  }
  c4[idx] = cn;
  hm4[idx] = hv;
  if (outc4) outc4[idx] = cn;
  int row = (int)(idx >> 5);
  float pwv = pw[row & 255];
  __shared__ float4 pp[256];
  pp[tid] = make_float4(hv.x*pwv, hv.y*pwv, hv.z*pwv, hv.w*pwv);
  __syncthreads();
  if (tid < 32) {
    float4 sa = pp[tid];
    #pragma unroll
    for (int k = 1; k < 8; ++k) {
      float4 v = pp[tid + k*32];
      sa.x += v.x; sa.y += v.y; sa.z += v.z; sa.w += v.w;
    }
    qpart[(size_t)blockIdx.x*32 + tid] = sa;
  }
}

// ---------------- K5: MFMA fatt: t=tanh(hmid@linh^T+qq); a=sig(t.luw+b); h*(1+a) ----------------
__global__ __launch_bounds__(256) void k5_fatt(const float* __restrict__ hmid,
    const float* __restrict__ qpartF, const float* __restrict__ pb,
    const float* __restrict__ lqw, const float* __restrict__ lqb,
    const float* __restrict__ lhb, const uint4* __restrict__ LhH,
    const uint4* __restrict__ LhL, const float* __restrict__ luw,
    const float* __restrict__ lub,
    float* __restrict__ hstate, float* __restrict__ out, int t,
    float* __restrict__ outh)
{
  const int tid = threadIdx.x, lane = tid & 63, w = tid >> 6;
  const int row0 = blockIdx.x * 64;
  const int b = row0 >> 8;
  __shared__ __align__(16) uint4 SH[2048];     // AH | AL (hmid rows, bf16 hi/lo)
  __shared__ float otile[HIDD][65];            // transposed out tile
  __shared__ float qsum[HIDD];
  __shared__ float qqL[HIDD];
  uint4* AH = SH;
  uint4* AL = SH + 1024;

  #pragma unroll
  for (int it = 0; it < 4; ++it) {
    int linear = it*256 + tid;
    int r = linear >> 4, blk = linear & 15;
    const float4* p = reinterpret_cast<const float4*>(hmid + (size_t)(row0 + r)*HIDD);
    float4 v0 = p[blk*2], v1 = p[blk*2 + 1];
    float vv[8] = {v0.x, v0.y, v0.z, v0.w, v1.x, v1.y, v1.z, v1.w};
    uint32_t uh[4], ul[4];
    #pragma unroll
    for (int j = 0; j < 4; ++j) {
      uint16_t h0 = bf16rn(vv[2*j]), h1 = bf16rn(vv[2*j+1]);
      uint16_t l0 = bf16rn(vv[2*j]   - bf16f(h0));
      uint16_t l1 = bf16rn(vv[2*j+1] - bf16f(h1));
      uh[j] = (uint32_t)h0 | ((uint32_t)h1 << 16);
      ul[j] = (uint32_t)l0 | ((uint32_t)l1 << 16);
    }
    int dst = r*16 + (blk ^ (r & 7));
    AH[dst] = make_uint4(uh[0], uh[1], uh[2], uh[3]);
    AL[dst] = make_uint4(ul[0], ul[1], ul[2], ul[3]);
  }
  if (tid < 128) {
    const float* qp = qpartF + (size_t)b*4096;
    float q = 0.f;
    #pragma unroll 8
    for (int p = 0; p < 32; ++p) q += qp[p*128 + tid];
    qsum[tid] = fmaxf(q + pb[0], 0.f);
  }
  __syncthreads();
  const int kg = lane >> 4;
  bf16x8 ah[4], al[4];
  {
    int i = w*16 + (lane & 15);
    #pragma unroll
    for (int ks = 0; ks < 4; ++ks) {
      int blk = (ks*4 + kg) ^ (i & 7);
      ah[ks] = *reinterpret_cast<const bf16x8*>(&AH[i*16 + blk]);
      al[ks] = *reinterpret_cast<const bf16x8*>(&AL[i*16 + blk]);
    }
  }
  if (tid < 128) {
    float acc = 0.f;
    #pragma unroll 4
    for (int k = 0; k < HIDD; ++k) acc += qsum[k]*lqw[tid*HIDD + k];
    qqL[tid] = acc + lqb[tid] + lhb[tid];
  }
  __syncthreads();

  f32x4 acc[8];
  #pragma unroll
  for (int c = 0; c < 8; ++c) acc[c] = (f32x4){0.f, 0.f, 0.f, 0.f};
  #pragma unroll
  for (int cf = 0; cf < 8; ++cf) {
    bf16x8 bh[4], bl[4];
    #pragma unroll
    for (int ks = 0; ks < 4; ++ks) {
      bh[ks] = *reinterpret_cast<const bf16x8*>(&LhH[(cf*4 + ks)*64 + lane]);
      bl[ks] = *reinterpret_cast<const bf16x8*>(&LhL[(cf*4 + ks)*64 + lane]);
    }
    #pragma unroll
    for (int ks = 0; ks < 4; ++ks) {
      acc[cf] = __builtin_amdgcn_mfma_f32_16x16x32_bf16(ah[ks], bh[ks], acc[cf], 0, 0, 0);
      acc[cf] = __builtin_amdgcn_mfma_f32_16x16x32_bf16(al[ks], bh[ks], acc[cf], 0, 0, 0);
      acc[cf] = __builtin_amdgcn_mfma_f32_16x16x32_bf16(ah[ks], bl[ks], acc[cf], 0, 0, 0);
    }
  }

  float apv[4] = {0.f, 0.f, 0.f, 0.f};
  #pragma unroll
  for (int cf = 0; cf < 8; ++cf) {
    int col = cf*16 + (lane & 15);
    float lu = luw[col];
    float qv = qqL[col];
    #pragma unroll
    for (int ii = 0; ii < 4; ++ii)
      apv[ii] += ftanh(acc[cf][ii] + qv) * lu;
  }
  #pragma unroll
  for (int off = 1; off < 16; off <<= 1) {
    #pragma unroll
    for (int ii = 0; ii < 4; ++ii)
      apv[ii] += __shfl_xor(apv[ii], off, 64);
  }
  float lb = lub[0];
  float av[4];
  #pragma unroll
  for (int ii = 0; ii < 4; ++ii)
    av[ii] = 1.f + fsig(apv[ii] + lb);

  #pragma unroll
  for (int cf = 0; cf < 8; ++cf) {
    int col = cf*16 + (lane & 15);
    #pragma unroll
    for (int ii = 0; ii < 4; ++ii) {
      int rloc = w*16 + (lane >> 4)*4 + ii;
      int row = row0 + rloc;
      float h = hmid[(size_t)row*HIDD + col];
      float v = h*av[ii];
      hstate[(size_t)row*HIDD + col] = v;
      if (outh) outh[(size_t)row*HIDD + col] = v;
      otile[col][rloc] = v;
    }
  }
  __syncthreads();
  #pragma unroll
  for (int i = 0; i < 32; ++i) {
    int idx = tid + i*256;
    int h = idx >> 6, rr = idx & 63;
    out[(size_t)h*(TT*(size_t)BSZ) + (size_t)t*BSZ + row0 + rr] = otile[h][rr];
  }
}

extern "C" void kernel_launch(void* const* d_in, const int* in_sizes, int n_in,
                              void* d_out, int out_size, void* d_ws, size_t ws_size,
                              hipStream_t stream)
{
  const float* x = (const float*)d_in[0];
  GP gp;
  int wIdx[8], aIdx[8], bIdx[4];
  bool dictOrder = (in_sizes[5] == HIDD);
  if (dictOrder) {
    for (int g = 0; g < 4; ++g) {
      int base = 1 + 5*g;
      wIdx[g]   = base;     aIdx[g]   = base + 1;
      wIdx[4+g] = base + 2; aIdx[4+g] = base + 3;
      bIdx[g]   = base + 4;
    }
  } else {
    for (int g = 0; g < 4; ++g) {
      int base = 1 + 4*g;
      wIdx[g]   = base;     aIdx[g]   = base + 1;
      wIdx[4+g] = base + 2; aIdx[4+g] = base + 3;
      bIdx[g]   = 17 + g;
    }
  }
  for (int s = 0; s < 8; ++s) {
    gp.W[s] = (const float*)d_in[wIdx[s]];
    gp.A[s] = (const float*)d_in[aIdx[s]];
  }
  const float* bi  = (const float*)d_in[bIdx[0]];
  const float* bf  = (const float*)d_in[bIdx[1]];
  const float* bc  = (const float*)d_in[bIdx[2]];
  const float* bo  = (const float*)d_in[bIdx[3]];
  const float* pw  = (const float*)d_in[21];
  const float* pb  = (const float*)d_in[22];
  const float* lhw = (const float*)d_in[23];
  const float* lhb = (const float*)d_in[24];
  const float* lqw = (const float*)d_in[25];
  const float* lqb = (const float*)d_in[26];
  const float* luw = (const float*)d_in[27];
  const float* lub = (const float*)d_in[28];

  const size_t S = (size_t)BSZ*HIDD;       // 1048576
  float* ws = (float*)d_ws;
  uint16_t* gatH = (uint16_t*)ws;          // 8*S u16 = 16 MB (= 4*S floats)
  float* hstate = ws + 4*S;                // S
  float* cstate = hstate + S;              // S
  float* hmid   = cstate + S;              // S
  float* f12U   = hmid + S;                // 131072
  float* qpart  = f12U + 131072;           // 131072
  float* Wa     = qpart + 131072;          // 2048
  uint4* WfH    = (uint4*)(Wa + 2048);     // 16384 uint4
  uint4* WfL    = WfH + 16384;             // 16384 uint4
  uint4* LhH    = WfL + 16384;             // 2048 uint4
  uint4* LhL    = LhH + 2048;              // 2048 uint4
  uint4* HfU    = LhL + 2048;              // 8*NB*4096 uint4 = 16 MB (4 used in pre)
  uint4* HfW    = HfU + (size_t)8*NB*4096;    // 64*NB*4096 uint4 = 128 MB
  float* f12W   = (float*)(HfW + (size_t)64*NB*4096);  // 64*2*BSZ = 4 MB
  bool pre = ws_size >= (size_t)205*1024*1024;

  float* out = (float*)d_out;
  const size_t off = (size_t)HIDD * (size_t)TT * (size_t)BSZ;  // 16777216

  hipMemsetAsync(hstate, 0, S*sizeof(float), stream);
  hipMemsetAsync(cstate, 0, S*sizeof(float), stream);
  k0_convw<<<8, 256, 0, stream>>>(gp, WfH, WfL);
  k0_wa<<<8, 128, 0, stream>>>(gp, Wa);
  k0_lh<<<1, 256, 0, stream>>>(lhw, LhH, LhL);

  if (pre) {
    // all W-side GEMMs for all t: grid y = t, 4 gates per block (2048 blocks)
    k1_gemm<4><<<dim3(128, 16), 256, 0, stream>>>(x, hstate, WfH, WfL, Wa,
        HfW, f12W, 0, 1, 0);
  }

  for (int t = 0; t < TT; ++t) {
    bool last = (t == TT - 1);
    if (pre) {
      // U-side: 1 gate per block, 512 blocks
      k1_gemm<1><<<dim3(128, 4), 256, 0, stream>>>(x, hstate, WfH, WfL, Wa,
          HfU, f12U, 4, 0, t);
      k2_attn<<<dim3(NB, 8, 4), 256, 0, stream>>>(HfW, HfU, f12W, f12U, gatH, t, 1);
    } else {
      k1_gemm<1><<<dim3(128, 8), 256, 0, stream>>>(x, hstate, WfH, WfL, Wa,
          HfU, f12U, 0, 0, t);
      k2_attn<<<dim3(NB, 8, 4), 256, 0, stream>>>(HfU, HfU, f12U, f12U, gatH, t, 0);
    }
    k3_gates<<<1024, 256, 0, stream>>>(gatH, (const float4*)bi,
        (const float4*)bf, (const float4*)bc, (const float4*)bo,
        (float4*)cstate, (float4*)hmid,
        last ? (float4*)(out + off + S) : (float4*)nullptr,
        pw, (float4*)qpart);
    k5_fatt<<<128, 256, 0, stream>>>(hmid, qpart, pb, lqw, lqb, lhb,
        LhH, LhL, luw, lub, hstate, out, t, last ? (out + off) : nullptr);
  }
}

// Round 19
// 1081.268 us; speedup vs baseline: 1.0491x; 1.0491x over previous
//
#include <hip/hip_runtime.h>
#include <cstdint>
#include <cstddef>

#define NN   256      // nodes
#define HIDD 128      // hidden
#define NB   32       // graphs per batch
#define TT   16       // timesteps
#define BSZ  (NB*NN)  // 8192 rows

struct GP {
  const float* W[8];  // s=0..3: Wi,Wf,Wc,Wo ; s=4..7: Ui,Uf,Uc,Uo
  const float* A[8];  // matching a-vectors (256,)
};

typedef __attribute__((ext_vector_type(8))) short bf16x8;
typedef __attribute__((ext_vector_type(4))) float f32x4;
typedef _Float16 f16x8 __attribute__((ext_vector_type(8)));

__device__ __forceinline__ uint16_t bf16rn(float f) {
  uint32_t u = __float_as_uint(f);
  uint32_t r = u + 0x7fffu + ((u >> 16) & 1u);
  return (uint16_t)(r >> 16);
}
__device__ __forceinline__ float bf16f(uint16_t h) {
  return __uint_as_float((uint32_t)h << 16);
}
__device__ __forceinline__ uint16_t f16b(float f) {
  union { _Float16 h; uint16_t u; } cv;
  cv.h = (_Float16)f;
  return cv.u;
}
__device__ __forceinline__ float f16f(uint16_t u) {
  union { uint16_t u; _Float16 h; } cv;
  cv.u = u;
  return (float)cv.h;
}
__device__ __forceinline__ float h4(uint2 v, int j) {
  uint32_t u = ((j < 2) ? v.x : v.y) >> ((j & 1)*16);
  return f16f((uint16_t)u);
}
__device__ __forceinline__ float fsig(float x) {
  return 1.f/(1.f + __expf(-x));
}
__device__ __forceinline__ float ftanh(float x) {
  float xc = fmaxf(-44.f, fminf(44.f, x));
  float e = __expf(-2.f*xc);
  return (1.f - e)/(1.f + e);
}

// ---------------- K0: pre-convert W[s] to fragment-ordered bf16 hi/lo ----------------
__global__ __launch_bounds__(256) void k0_convw(GP gp, uint4* __restrict__ WfH,
    uint4* __restrict__ WfL)
{
  const int s = blockIdx.x;
  const float* __restrict__ W = gp.W[s];
  const int tid = threadIdx.x;
  #pragma unroll
  for (int it = 0; it < 8; ++it) {
    int f = it*256 + tid;               // 0..2047
    int cf = f >> 8, ks = (f >> 6) & 3, l = f & 63;
    int col = cf*16 + (l & 15);
    int kbase = (ks*4 + (l >> 4))*8;
    float v[8];
    #pragma unroll
    for (int j = 0; j < 8; ++j) v[j] = W[(kbase + j)*HIDD + col];
    uint32_t uh[4], ul[4];
    #pragma unroll
    for (int j = 0; j < 4; ++j) {
      uint16_t h0 = bf16rn(v[2*j]), h1 = bf16rn(v[2*j+1]);
      uint16_t l0 = bf16rn(v[2*j]   - bf16f(h0));
      uint16_t l1 = bf16rn(v[2*j+1] - bf16f(h1));
      uh[j] = (uint32_t)h0 | ((uint32_t)h1 << 16);
      ul[j] = (uint32_t)l0 | ((uint32_t)l1 << 16);
    }
    WfH[s*2048 + f] = make_uint4(uh[0], uh[1], uh[2], uh[3]);
    WfL[s*2048 + f] = make_uint4(ul[0], ul[1], ul[2], ul[3]);
  }
}

// ---------------- K0L: pre-convert linh^T to fragment-ordered bf16 hi/lo ----------------
__global__ __launch_bounds__(256) void k0_lh(const float* __restrict__ lhw,
    uint4* __restrict__ LhH, uint4* __restrict__ LhL)
{
  const int tid = threadIdx.x;
  #pragma unroll
  for (int it = 0; it < 8; ++it) {
    int f = it*256 + tid;               // 0..2047
    int cf = f >> 8, ks = (f >> 6) & 3, l = f & 63;
    int col = cf*16 + (l & 15);
    int kbase = (ks*4 + (l >> 4))*8;
    float v[8];
    #pragma unroll
    for (int j = 0; j < 8; ++j) v[j] = lhw[col*HIDD + kbase + j];
    uint32_t uh[4], ul[4];
    #pragma unroll
    for (int j = 0; j < 4; ++j) {
      uint16_t h0 = bf16rn(v[2*j]), h1 = bf16rn(v[2*j+1]);
      uint16_t l0 = bf16rn(v[2*j]   - bf16f(h0));
      uint16_t l1 = bf16rn(v[2*j+1] - bf16f(h1));
      uh[j] = (uint32_t)h0 | ((uint32_t)h1 << 16);
      ul[j] = (uint32_t)l0 | ((uint32_t)l1 << 16);
    }
    LhH[f] = make_uint4(uh[0], uh[1], uh[2], uh[3]);
    LhL[f] = make_uint4(ul[0], ul[1], ul[2], ul[3]);
  }
}

// ---------------- K0b: Wa[s][k] = sum_c W[k][c]*a{1,2}[c] ----------------
__global__ __launch_bounds__(128) void k0_wa(GP gp, float* __restrict__ Wa)
{
  const int s = blockIdx.x, k = threadIdx.x;
  const float* __restrict__ W = gp.W[s];
  const float* __restrict__ A = gp.A[s];
  float d1 = 0.f, d2 = 0.f;
  #pragma unroll 4
  for (int c = 0; c < HIDD; ++c) {
    float wv = W[k*HIDD + c];
    d1 += wv*A[c];
    d2 += wv*A[HIDD + c];
  }
  Wa[s*256 + k]       = d1;
  Wa[s*256 + 128 + k] = d2;
}

// ---------------- K1: src @ W_s -> H fragments (fp16) + f1/f2, NG gates/block ----------------
// 64-row tiles, 256 threads. Direct fragment stores from MFMA acc registers.
template<int NG>
__global__ __launch_bounds__(256) void k1_gemm(const float* __restrict__ x,
    const float* __restrict__ hstate, const uint4* __restrict__ WfH,
    const uint4* __restrict__ WfL, const float* __restrict__ Wa,
    uint4* __restrict__ HfO, float* __restrict__ f12,
    int sBase, int wside, int tArg)
{
  const int t = wside ? blockIdx.y : tArg;
  const int s0 = wside ? 0 : (sBase + blockIdx.y*NG);
  const int row0 = blockIdx.x * 64;
  const int b = row0 >> 8;
  const int kc = (row0 >> 6) & 3;
  const int tid = threadIdx.x, lane = tid & 63, w = tid >> 6;
  __shared__ __align__(16) uint4 AH[1024];       // 16 KB source hi
  __shared__ __align__(16) uint4 AL[1024];       // 16 KB source lo
  __shared__ float red1[2][4][64], red2[2][4][64];  // parity double-buffer, 4 KB
  const bool useX = wside || (s0 < 4);

  // stage source rows once: hi/lo bf16 (16B-block XOR swizzle by row&7)
  #pragma unroll
  for (int it = 0; it < 4; ++it) {
    int linear = it*256 + tid;          // 0..1023
    int r = linear >> 4, blk = linear & 15;
    const float4* p = useX
      ? reinterpret_cast<const float4*>(x + (size_t)(row0 + r)*(TT*HIDD) + (size_t)t*HIDD)
      : reinterpret_cast<const float4*>(hstate + (size_t)(row0 + r)*HIDD);
    float4 v0 = p[blk*2], v1 = p[blk*2 + 1];
    float vv[8] = {v0.x, v0.y, v0.z, v0.w, v1.x, v1.y, v1.z, v1.w};
    uint32_t uh[4], ul[4];
    #pragma unroll
    for (int j = 0; j < 4; ++j) {
      uint16_t h0 = bf16rn(vv[2*j]), h1 = bf16rn(vv[2*j+1]);
      uint16_t l0 = bf16rn(vv[2*j]   - bf16f(h0));
      uint16_t l1 = bf16rn(vv[2*j+1] - bf16f(h1));
      uh[j] = (uint32_t)h0 | ((uint32_t)h1 << 16);
      ul[j] = (uint32_t)l0 | ((uint32_t)l1 << 16);
    }
    int dst = r*16 + (blk ^ (r & 7));
    AH[dst] = make_uint4(uh[0], uh[1], uh[2], uh[3]);
    AL[dst] = make_uint4(ul[0], ul[1], ul[2], ul[3]);
  }
  __syncthreads();

  // A-fragment register loads once (shared across gates)
  const int kg = lane >> 4;
  bf16x8 ah[4], al[4];
  {
    int i = w*16 + (lane & 15);
    #pragma unroll
    for (int ks = 0; ks < 4; ++ks) {
      int blk = (ks*4 + kg) ^ (i & 7);
      ah[ks] = *reinterpret_cast<const bf16x8*>(&AH[i*16 + blk]);
      al[ks] = *reinterpret_cast<const bf16x8*>(&AL[i*16 + blk]);
    }
  }
  const int frow = tid & 63, kq = tid >> 6;
  // direct-store geometry (constant per thread)
  const int jlb = w*16 + (lane >> 4)*4;                 // local row base
  const int ksS = jlb >> 5;                             // fragment k-step
  const int l2S = (((jlb & 31) >> 3) << 4) | (lane & 15);
  const int hoff = (jlb & 4)*2;                         // byte offset of uint2 half

  #pragma unroll 1
  for (int gi = 0; gi < NG; ++gi) {
    const int s = wside ? gi : (s0 + gi);
    const int tIdx = wside ? (t*4 + gi) : (s - sBase);
    const int par = gi & 1;
    // f1/f2 partials (LDS reads; AH/AL stay intact)
    {
      const float* __restrict__ wa = Wa + s*256;
      float d1 = 0.f, d2 = 0.f;
      #pragma unroll
      for (int bb = 0; bb < 4; ++bb) {
        int bi = kq*4 + bb;
        uint4 vh = AH[frow*16 + (bi ^ (frow & 7))];
        uint4 vl = AL[frow*16 + (bi ^ (frow & 7))];
        #pragma unroll
        for (int j = 0; j < 4; ++j) {
          uint32_t uh = (&vh.x)[j], ul2 = (&vl.x)[j];
          float e0 = __uint_as_float(uh << 16) + __uint_as_float(ul2 << 16);
          float e1 = __uint_as_float(uh & 0xffff0000u) + __uint_as_float(ul2 & 0xffff0000u);
          int k0 = bi*8 + j*2;
          d1 += e0*wa[k0]     + e1*wa[k0+1];
          d2 += e0*wa[128+k0] + e1*wa[128+k0+1];
        }
      }
      red1[par][kq][frow] = d1; red2[par][kq][frow] = d2;
    }
    // MFMA (split bf16: hh + lh + hl)
    f32x4 acc[8];
    #pragma unroll
    for (int c = 0; c < 8; ++c) acc[c] = (f32x4){0.f, 0.f, 0.f, 0.f};
    const uint4* __restrict__ BH = WfH + s*2048;
    const uint4* __restrict__ BL = WfL + s*2048;
    #pragma unroll
    for (int cf = 0; cf < 8; ++cf) {
      bf16x8 bh[4], bl[4];
      #pragma unroll
      for (int ks = 0; ks < 4; ++ks) {
        bh[ks] = *reinterpret_cast<const bf16x8*>(&BH[(cf*4 + ks)*64 + lane]);
        bl[ks] = *reinterpret_cast<const bf16x8*>(&BL[(cf*4 + ks)*64 + lane]);
      }
      #pragma unroll
      for (int ks = 0; ks < 4; ++ks) {
        acc[cf] = __builtin_amdgcn_mfma_f32_16x16x32_bf16(ah[ks], bh[ks], acc[cf], 0, 0, 0);
        acc[cf] = __builtin_amdgcn_mfma_f32_16x16x32_bf16(al[ks], bh[ks], acc[cf], 0, 0, 0);
        acc[cf] = __builtin_amdgcn_mfma_f32_16x16x32_bf16(ah[ks], bl[ks], acc[cf], 0, 0, 0);
      }
    }
    __syncthreads();   // red[par] visible to f12-store threads
    if (tid < 64) {
      float* fb = f12 + (size_t)tIdx*2*BSZ;
      fb[row0 + tid]       = red1[par][0][tid] + red1[par][1][tid] + red1[par][2][tid] + red1[par][3][tid];
      fb[BSZ + row0 + tid] = red2[par][0][tid] + red2[par][1][tid] + red2[par][2][tid] + red2[par][3][tid];
    }
    // direct fragment stores (coalesced uint2 per cf)
    {
      char* HfB = reinterpret_cast<char*>(HfO + (size_t)(tIdx*NB + b)*4096);
      #pragma unroll
      for (int cf = 0; cf < 8; ++cf) {
        uint16_t hh[4];
        #pragma unroll
        for (int ii = 0; ii < 4; ++ii) hh[ii] = f16b(acc[cf][ii]);
        size_t fg = (size_t)((kc*2 + ksS)*8 + cf)*64 + l2S;
        *reinterpret_cast<uint2*>(HfB + fg*16 + hoff) =
            make_uint2((uint32_t)hh[0] | ((uint32_t)hh[1] << 16),
                       (uint32_t)hh[2] | ((uint32_t)hh[3] << 16));
      }
    }
  }
}

// ---------------- K2: gat[s] = elu(softmax(leaky(f1_i+f2_j)) @ h) -> fp16 ----------------
__global__ __launch_bounds__(256) void k2_attn(
    const uint4* __restrict__ HfW, const uint4* __restrict__ HfU,
    const float* __restrict__ f12W, const float* __restrict__ f12U,
    uint16_t* __restrict__ gatH, int t, int pre)
{
  const int s = blockIdx.y;
  const int b = blockIdx.x;
  const int roff = blockIdx.z * 64;
  const int tid = threadIdx.x, lane = tid & 63, w = tid >> 6;
  const int rl = tid & 63, qh = tid >> 6;     // row-local, j-quarter
  __shared__ __align__(16) float f2L[NN];
  __shared__ __align__(16) float sums[256];
  __shared__ __align__(16) uint16_t Pb[64*64];   // 8 KB fp16 [row][64j] swizzled
  const uint4 *BH;
  const float* fb;
  if (pre && s < 4) {
    size_t tg = (size_t)(t*4 + s);
    BH = HfW + (tg*NB + b)*4096;
    fb = f12W + tg*2*BSZ;
  } else {
    size_t tg = (size_t)(s - (pre ? 4 : 0));
    BH = HfU + (tg*NB + b)*4096;
    fb = f12U + tg*2*BSZ;
  }
  f2L[tid] = fb[BSZ + b*NN + tid];
  const float f1v = fb[b*NN + roff + rl];

  const float4* f24 = reinterpret_cast<const float4*>(f2L);
  float ssum = 0.f;
  f32x4 acc[8];
  #pragma unroll
  for (int c = 0; c < 8; ++c) acc[c] = (f32x4){0.f, 0.f, 0.f, 0.f};
  char* PbB = reinterpret_cast<char*>(Pb);
  const int kg = lane >> 4;

  for (int kc = 0; kc < 4; ++kc) {
    __syncthreads();
    #pragma unroll
    for (int bb = 0; bb < 2; ++bb) {
      int blk = qh*2 + bb;
      float4 va = f24[kc*16 + blk*2];
      float4 vb = f24[kc*16 + blk*2 + 1];
      float e0 = f1v + va.x; e0 = e0 > 0.f ? e0 : 0.01f*e0;
      float e1 = f1v + va.y; e1 = e1 > 0.f ? e1 : 0.01f*e1;
      float e2 = f1v + va.z; e2 = e2 > 0.f ? e2 : 0.01f*e2;
      float e3 = f1v + va.w; e3 = e3 > 0.f ? e3 : 0.01f*e3;
      float e4 = f1v + vb.x; e4 = e4 > 0.f ? e4 : 0.01f*e4;
      float e5 = f1v + vb.y; e5 = e5 > 0.f ? e5 : 0.01f*e5;
      float e6 = f1v + vb.z; e6 = e6 > 0.f ? e6 : 0.01f*e6;
      float e7 = f1v + vb.w; e7 = e7 > 0.f ? e7 : 0.01f*e7;
      float p0 = __expf(e0), p1 = __expf(e1), p2 = __expf(e2), p3 = __expf(e3);
      float p4 = __expf(e4), p5 = __expf(e5), p6 = __expf(e6), p7 = __expf(e7);
      ssum += (p0 + p1) + (p2 + p3) + ((p4 + p5) + (p6 + p7));
      uint32_t u0 = (uint32_t)f16b(p0) | ((uint32_t)f16b(p1) << 16);
      uint32_t u1 = (uint32_t)f16b(p2) | ((uint32_t)f16b(p3) << 16);
      uint32_t u2 = (uint32_t)f16b(p4) | ((uint32_t)f16b(p5) << 16);
      uint32_t u3 = (uint32_t)f16b(p6) | ((uint32_t)f16b(p7) << 16);
      *reinterpret_cast<uint4*>(PbB + rl*128 + ((blk ^ (rl & 7)) << 4)) =
          make_uint4(u0, u1, u2, u3);
    }
    __syncthreads();
    #pragma unroll
    for (int ks = 0; ks < 2; ++ks) {
      int i = w*16 + (lane & 15);
      int blk = (ks*4 + kg) ^ (i & 7);
      f16x8 af = *reinterpret_cast<const f16x8*>(PbB + i*128 + blk*16);
      #pragma unroll
      for (int c = 0; c < 8; ++c) {
        size_t fg = (size_t)((kc*2 + ks)*8 + c)*64 + lane;
        f16x8 bh = *reinterpret_cast<const f16x8*>(&BH[fg]);
        acc[c] = __builtin_amdgcn_mfma_f32_16x16x32_f16(af, bh, acc[c], 0, 0, 0);
      }
    }
  }
  sums[tid] = ssum;
  __syncthreads();

  uint16_t* __restrict__ gout = gatH + ((size_t)s*BSZ + (size_t)b*NN)*HIDD;
  {
    int lrb = w*16 + (lane >> 4)*4;
    int row = roff + lrb;
    #pragma unroll
    for (int ii = 0; ii < 4; ++ii) {
      float rs = 1.f / (sums[lrb + ii] + sums[64 + lrb + ii] +
                        sums[128 + lrb + ii] + sums[192 + lrb + ii]);
      #pragma unroll
      for (int c = 0; c < 8; ++c) {
        int col = c*16 + (lane & 15);
        float v = acc[c][ii] * rs;
        v = v > 0.f ? v : (__expf(v) - 1.f);
        gout[(size_t)(row + ii)*HIDD + col] = f16b(v);
      }
    }
  }
}

// ---------------- K3: LSTM gate combine (fp16 gat) + pool partials ----------------
__global__ __launch_bounds__(256) void k3_gates(const uint16_t* __restrict__ gatH,
    const float4* __restrict__ bi4, const float4* __restrict__ bf4,
    const float4* __restrict__ bc4, const float4* __restrict__ bo4,
    float4* __restrict__ c4, float4* __restrict__ hm4, float4* __restrict__ outc4,
    const float* __restrict__ pw, float4* __restrict__ qpart)
{
  const size_t S4h = (size_t)BSZ*HIDD/4;     // uint2 (4 halves) per buffer
  const int tid = threadIdx.x;
  size_t idx = (size_t)blockIdx.x*256 + tid;
  int hc = (int)(idx & 31);
  const uint2* gH = reinterpret_cast<const uint2*>(gatH);
  uint2 g0 = gH[idx],          g1 = gH[S4h + idx];
  uint2 g2 = gH[2*S4h + idx],  g3 = gH[3*S4h + idx];
  uint2 g4 = gH[4*S4h + idx],  g5 = gH[5*S4h + idx];
  uint2 g6 = gH[6*S4h + idx],  g7 = gH[7*S4h + idx];
  float4 Bi = bi4[hc], Bf = bf4[hc], Bc = bc4[hc], Bo = bo4[hc];
  float4 cv = c4[idx], hv, cn;
  #pragma unroll
  for (int j = 0; j < 4; ++j) {
    float xi = h4(g0, j) + h4(g4, j) + (&Bi.x)[j];
    float xf = h4(g1, j) + h4(g5, j) + (&Bf.x)[j];
    float xc = h4(g2, j) + h4(g6, j) + (&Bc.x)[j];
    float xo = h4(g3, j) + h4(g7, j) + (&Bo.x)[j];
    float it = fsig(xi);
    float ft = fsig(xf);
    float gt = ftanh(xc);
    float ot = fsig(xo);
    float c = ft*(&cv.x)[j] + it*gt;
    (&cn.x)[j] = c;
    (&hv.x)[j] = ot*ftanh(c);
  }
  c4[idx] = cn;
  hm4[idx] = hv;
  if (outc4) outc4[idx] = cn;
  int row = (int)(idx >> 5);
  float pwv = pw[row & 255];
  __shared__ float4 pp[256];
  pp[tid] = make_float4(hv.x*pwv, hv.y*pwv, hv.z*pwv, hv.w*pwv);
  __syncthreads();
  if (tid < 32) {
    float4 sa = pp[tid];
    #pragma unroll
    for (int k = 1; k < 8; ++k) {
      float4 v = pp[tid + k*32];
      sa.x += v.x; sa.y += v.y; sa.z += v.z; sa.w += v.w;
    }
    qpart[(size_t)blockIdx.x*32 + tid] = sa;
  }
}

// ---------------- K5: MFMA fatt: t=tanh(hmid@linh^T+qq); a=sig(t.luw+b); h*(1+a) ----------------
__global__ __launch_bounds__(256) void k5_fatt(const float* __restrict__ hmid,
    const float* __restrict__ qpartF, const float* __restrict__ pb,
    const float* __restrict__ lqw, const float* __restrict__ lqb,
    const float* __restrict__ lhb, const uint4* __restrict__ LhH,
    const uint4* __restrict__ LhL, const float* __restrict__ luw,
    const float* __restrict__ lub,
    float* __restrict__ hstate, float* __restrict__ out, int t,
    float* __restrict__ outh)
{
  const int tid = threadIdx.x, lane = tid & 63, w = tid >> 6;
  const int row0 = blockIdx.x * 64;
  const int b = row0 >> 8;
  __shared__ __align__(16) uint4 SH[2048];     // AH | AL (hmid rows, bf16 hi/lo)
  __shared__ float otile[HIDD][65];            // transposed out tile
  __shared__ float qsum[HIDD];
  __shared__ float qqL[HIDD];
  uint4* AH = SH;
  uint4* AL = SH + 1024;

  #pragma unroll
  for (int it = 0; it < 4; ++it) {
    int linear = it*256 + tid;
    int r = linear >> 4, blk = linear & 15;
    const float4* p = reinterpret_cast<const float4*>(hmid + (size_t)(row0 + r)*HIDD);
    float4 v0 = p[blk*2], v1 = p[blk*2 + 1];
    float vv[8] = {v0.x, v0.y, v0.z, v0.w, v1.x, v1.y, v1.z, v1.w};
    uint32_t uh[4], ul[4];
    #pragma unroll
    for (int j = 0; j < 4; ++j) {
      uint16_t h0 = bf16rn(vv[2*j]), h1 = bf16rn(vv[2*j+1]);
      uint16_t l0 = bf16rn(vv[2*j]   - bf16f(h0));
      uint16_t l1 = bf16rn(vv[2*j+1] - bf16f(h1));
      uh[j] = (uint32_t)h0 | ((uint32_t)h1 << 16);
      ul[j] = (uint32_t)l0 | ((uint32_t)l1 << 16);
    }
    int dst = r*16 + (blk ^ (r & 7));
    AH[dst] = make_uint4(uh[0], uh[1], uh[2], uh[3]);
    AL[dst] = make_uint4(ul[0], ul[1], ul[2], ul[3]);
  }
  if (tid < 128) {
    const float* qp = qpartF + (size_t)b*4096;
    float q = 0.f;
    #pragma unroll 8
    for (int p = 0; p < 32; ++p) q += qp[p*128 + tid];
    qsum[tid] = fmaxf(q + pb[0], 0.f);
  }
  __syncthreads();
  const int kg = lane >> 4;
  bf16x8 ah[4], al[4];
  {
    int i = w*16 + (lane & 15);
    #pragma unroll
    for (int ks = 0; ks < 4; ++ks) {
      int blk = (ks*4 + kg) ^ (i & 7);
      ah[ks] = *reinterpret_cast<const bf16x8*>(&AH[i*16 + blk]);
      al[ks] = *reinterpret_cast<const bf16x8*>(&AL[i*16 + blk]);
    }
  }
  if (tid < 128) {
    float acc = 0.f;
    #pragma unroll 4
    for (int k = 0; k < HIDD; ++k) acc += qsum[k]*lqw[tid*HIDD + k];
    qqL[tid] = acc + lqb[tid] + lhb[tid];
  }
  __syncthreads();

  f32x4 acc[8];
  #pragma unroll
  for (int c = 0; c < 8; ++c) acc[c] = (f32x4){0.f, 0.f, 0.f, 0.f};
  #pragma unroll
  for (int cf = 0; cf < 8; ++cf) {
    bf16x8 bh[4], bl[4];
    #pragma unroll
    for (int ks = 0; ks < 4; ++ks) {
      bh[ks] = *reinterpret_cast<const bf16x8*>(&LhH[(cf*4 + ks)*64 + lane]);
      bl[ks] = *reinterpret_cast<const bf16x8*>(&LhL[(cf*4 + ks)*64 + lane]);
    }
    #pragma unroll
    for (int ks = 0; ks < 4; ++ks) {
      acc[cf] = __builtin_amdgcn_mfma_f32_16x16x32_bf16(ah[ks], bh[ks], acc[cf], 0, 0, 0);
      acc[cf] = __builtin_amdgcn_mfma_f32_16x16x32_bf16(al[ks], bh[ks], acc[cf], 0, 0, 0);
      acc[cf] = __builtin_amdgcn_mfma_f32_16x16x32_bf16(ah[ks], bl[ks], acc[cf], 0, 0, 0);
    }
  }

  float apv[4] = {0.f, 0.f, 0.f, 0.f};
  #pragma unroll
  for (int cf = 0; cf < 8; ++cf) {
    int col = cf*16 + (lane & 15);
    float lu = luw[col];
    float qv = qqL[col];
    #pragma unroll
    for (int ii = 0; ii < 4; ++ii)
      apv[ii] += ftanh(acc[cf][ii] + qv) * lu;
  }
  #pragma unroll
  for (int off = 1; off < 16; off <<= 1) {
    #pragma unroll
    for (int ii = 0; ii < 4; ++ii)
      apv[ii] += __shfl_xor(apv[ii], off, 64);
  }
  float lb = lub[0];
  float av[4];
  #pragma unroll
  for (int ii = 0; ii < 4; ++ii)
    av[ii] = 1.f + fsig(apv[ii] + lb);

  #pragma unroll
  for (int cf = 0; cf < 8; ++cf) {
    int col = cf*16 + (lane & 15);
    #pragma unroll
    for (int ii = 0; ii < 4; ++ii) {
      int rloc = w*16 + (lane >> 4)*4 + ii;
      int row = row0 + rloc;
      float h = hmid[(size_t)row*HIDD + col];
      float v = h*av[ii];
      hstate[(size_t)row*HIDD + col] = v;
      if (outh) outh[(size_t)row*HIDD + col] = v;
      otile[col][rloc] = v;
    }
  }
  __syncthreads();
  #pragma unroll
  for (int i = 0; i < 32; ++i) {
    int idx = tid + i*256;
    int h = idx >> 6, rr = idx & 63;
    out[(size_t)h*(TT*(size_t)BSZ) + (size_t)t*BSZ + row0 + rr] = otile[h][rr];
  }
}

extern "C" void kernel_launch(void* const* d_in, const int* in_sizes, int n_in,
                              void* d_out, int out_size, void* d_ws, size_t ws_size,
                              hipStream_t stream)
{
  const float* x = (const float*)d_in[0];
  GP gp;
  int wIdx[8], aIdx[8], bIdx[4];
  bool dictOrder = (in_sizes[5] == HIDD);
  if (dictOrder) {
    for (int g = 0; g < 4; ++g) {
      int base = 1 + 5*g;
      wIdx[g]   = base;     aIdx[g]   = base + 1;
      wIdx[4+g] = base + 2; aIdx[4+g] = base + 3;
      bIdx[g]   = base + 4;
    }
  } else {
    for (int g = 0; g < 4; ++g) {
      int base = 1 + 4*g;
      wIdx[g]   = base;     aIdx[g]   = base + 1;
      wIdx[4+g] = base + 2; aIdx[4+g] = base + 3;
      bIdx[g]   = 17 + g;
    }
  }
  for (int s = 0; s < 8; ++s) {
    gp.W[s] = (const float*)d_in[wIdx[s]];
    gp.A[s] = (const float*)d_in[aIdx[s]];
  }
  const float* bi  = (const float*)d_in[bIdx[0]];
  const float* bf  = (const float*)d_in[bIdx[1]];
  const float* bc  = (const float*)d_in[bIdx[2]];
  const float* bo  = (const float*)d_in[bIdx[3]];
  const float* pw  = (const float*)d_in[21];
  const float* pb  = (const float*)d_in[22];
  const float* lhw = (const float*)d_in[23];
  const float* lhb = (const float*)d_in[24];
  const float* lqw = (const float*)d_in[25];
  const float* lqb = (const float*)d_in[26];
  const float* luw = (const float*)d_in[27];
  const float* lub = (const float*)d_in[28];

  const size_t S = (size_t)BSZ*HIDD;       // 1048576
  float* ws = (float*)d_ws;
  uint16_t* gatH = (uint16_t*)ws;          // 8*S u16 = 16 MB (= 4*S floats)
  float* hstate = ws + 4*S;                // S
  float* cstate = hstate + S;              // S
  float* hmid   = cstate + S;              // S
  float* f12U   = hmid + S;                // 131072
  float* qpart  = f12U + 131072;           // 131072
  float* Wa     = qpart + 131072;          // 2048
  uint4* WfH    = (uint4*)(Wa + 2048);     // 16384 uint4
  uint4* WfL    = WfH + 16384;             // 16384 uint4
  uint4* LhH    = WfL + 16384;             // 2048 uint4
  uint4* LhL    = LhH + 2048;              // 2048 uint4
  uint4* HfU    = LhL + 2048;              // 8*NB*4096 uint4 = 16 MB (4 used in pre)
  uint4* HfW    = HfU + (size_t)8*NB*4096;    // 64*NB*4096 uint4 = 128 MB
  float* f12W   = (float*)(HfW + (size_t)64*NB*4096);  // 64*2*BSZ = 4 MB
  bool pre = ws_size >= (size_t)205*1024*1024;

  float* out = (float*)d_out;
  const size_t off = (size_t)HIDD * (size_t)TT * (size_t)BSZ;  // 16777216

  hipMemsetAsync(hstate, 0, S*sizeof(float), stream);
  hipMemsetAsync(cstate, 0, S*sizeof(float), stream);
  k0_convw<<<8, 256, 0, stream>>>(gp, WfH, WfL);
  k0_wa<<<8, 128, 0, stream>>>(gp, Wa);
  k0_lh<<<1, 256, 0, stream>>>(lhw, LhH, LhL);

  if (pre) {
    // all W-side GEMMs for all t: grid y = t, 4 gates per block (2048 blocks)
    k1_gemm<4><<<dim3(128, 16), 256, 0, stream>>>(x, hstate, WfH, WfL, Wa,
        HfW, f12W, 0, 1, 0);
  }

  for (int t = 0; t < TT; ++t) {
    bool last = (t == TT - 1);
    if (pre) {
      // U-side: 1 gate per block, 512 blocks (max parallelism)
      k1_gemm<1><<<dim3(128, 4), 256, 0, stream>>>(x, hstate, WfH, WfL, Wa,
          HfU, f12U, 4, 0, t);
      k2_attn<<<dim3(NB, 8, 4), 256, 0, stream>>>(HfW, HfU, f12W, f12U, gatH, t, 1);
    } else {
      k1_gemm<1><<<dim3(128, 8), 256, 0, stream>>>(x, hstate, WfH, WfL, Wa,
          HfU, f12U, 0, 0, t);
      k2_attn<<<dim3(NB, 8, 4), 256, 0, stream>>>(HfU, HfU, f12U, f12U, gatH, t, 0);
    }
    k3_gates<<<1024, 256, 0, stream>>>(gatH, (const float4*)bi,
        (const float4*)bf, (const float4*)bc, (const float4*)bo,
        (float4*)cstate, (float4*)hmid,
        last ? (float4*)(out + off + S) : (float4*)nullptr,
        pw, (float4*)qpart);
    k5_fatt<<<128, 256, 0, stream>>>(hmid, qpart, pb, lqw, lqb, lhb,
        LhH, LhL, luw, lub, hstate, out, t, last ? (out + off) : nullptr);
  }
}